// Round 1
// baseline (613.856 us; speedup 1.0000x reference)
//
#include <hip/hip_runtime.h>

// Problem constants
// x: [2][64][32][64][64] f32, w_q: [64][64], w_kv: [128][64][8][8][8], w_out: [64][64]
// out: [2][64][32][64][64] f32
#define NPOS 131072   // 32*64*64 query positions per batch
#define NR   256      // 4*8*8 key positions per batch
#define NHEAD 4
#define HD   16

// ---------------- K0: transpose the small 64x64 weights ----------------
__global__ void k_prep_w(const float* __restrict__ wq, const float* __restrict__ wout,
                         float* __restrict__ wq_t, float* __restrict__ wout_t) {
    int t = blockIdx.x * 256 + threadIdx.x;   // 0..4095
    int o = t >> 6, c = t & 63;
    wq_t[c * 64 + o]   = wq[o * 64 + c];
    wout_t[c * 64 + o] = wout[o * 64 + c];
}

// ---------------- K1: transpose w_kv[oc][ic][term] -> wt[ic][term][oc] ----------------
// grid: ic(64) x termblk(16) x ocblk(4) = 4096 blocks, 256 thr
__global__ void k_prep_wkv(const float* __restrict__ wkv, float* __restrict__ wt) {
    __shared__ float tile[32][33];
    int bid = blockIdx.x;
    int ic = bid >> 6;
    int tb = (bid >> 2) & 15;
    int ob = bid & 3;
    int lane = threadIdx.x & 31;
    int row  = threadIdx.x >> 5;   // 0..7
#pragma unroll
    for (int rr = 0; rr < 4; ++rr) {
        int r = row + rr * 8;      // oc offset 0..31
        tile[r][lane] = wkv[((size_t)(ob * 32 + r) * 64 + ic) * 512 + tb * 32 + lane];
    }
    __syncthreads();
#pragma unroll
    for (int rr = 0; rr < 4; ++rr) {
        int r = row + rr * 8;      // term offset 0..31
        wt[((size_t)ic * 512 + tb * 32 + r) * 128 + ob * 32 + lane] = tile[lane][r];
    }
}

// ---------------- K2: strided conv (kv), split-K over ic ----------------
// grid: b(2) x ic(64) x dz(4) = 512 blocks, 256 thr
// partial[ic][b][pos(256)][oc(128)]
__global__ __launch_bounds__(256) void k_conv(const float* __restrict__ x,
                                              const float* __restrict__ wt,
                                              float* __restrict__ partial) {
    __shared__ float plane[4096];   // one z-plane (64x64) of one input channel
    int bid = blockIdx.x;
    int b  = bid >> 8;
    int ic = (bid >> 2) & 63;
    int dz = bid & 3;
    int tid = threadIdx.x;
    int og = tid & 31;    // oc0 = og*4
    int dy = tid >> 5;    // 0..7

    float acc[8][4];
#pragma unroll
    for (int a = 0; a < 8; ++a)
#pragma unroll
        for (int k = 0; k < 4; ++k) acc[a][k] = 0.f;

    const float* xbase = x + ((size_t)b * 64 + ic) * NPOS + (size_t)dz * 8 * 4096;
    const float* wbase = wt + (size_t)ic * 512 * 128 + og * 4;

    for (int rz = 0; rz < 8; ++rz) {
        __syncthreads();
        const float4* src = (const float4*)(xbase + (size_t)rz * 4096);
        float4* dst = (float4*)plane;
#pragma unroll
        for (int t = 0; t < 4; ++t) dst[t * 256 + tid] = src[t * 256 + tid];
        __syncthreads();
        for (int ryx = 0; ryx < 64; ++ryx) {
            int term = rz * 64 + ryx;
            int ry = ryx >> 3, rx = ryx & 7;
            float4 w = *(const float4*)(wbase + (size_t)term * 128);
            const float* xr = plane + (dy * 8 + ry) * 64 + rx;
#pragma unroll
            for (int dxk = 0; dxk < 8; ++dxk) {
                float xv = xr[dxk * 8];
                acc[dxk][0] += xv * w.x;
                acc[dxk][1] += xv * w.y;
                acc[dxk][2] += xv * w.z;
                acc[dxk][3] += xv * w.w;
            }
        }
    }
    float* pb = partial + (((size_t)ic * 2 + b) * 256 + dz * 64 + dy * 8) * 128 + og * 4;
#pragma unroll
    for (int dxk = 0; dxk < 8; ++dxk) {
        *(float4*)(pb + (size_t)dxk * 128) =
            make_float4(acc[dxk][0], acc[dxk][1], acc[dxk][2], acc[dxk][3]);
    }
}

// ---------------- K3: reduce partials over ic, write K/V in [b][h][j][i] ----------------
// grid: 256 blocks x 256 thr = 65536 = 2*256*128
__global__ void k_reduce(const float* __restrict__ partial,
                         float* __restrict__ kt, float* __restrict__ vv) {
    int gid = blockIdx.x * 256 + threadIdx.x;
    int oc = gid & 127;
    int bp = gid >> 7;     // b*256 + j
    int b = bp >> 8;
    int j = bp & 255;
    const float* p = partial + (size_t)bp * 128 + oc;
    float s = 0.f;
#pragma unroll 8
    for (int ic = 0; ic < 64; ++ic) s += p[(size_t)ic * 65536];
    if (oc < 64) {
        int h = oc >> 4, i = oc & 15;
        kt[(((size_t)b * 4 + h) * 256 + j) * 16 + i] = s;
    } else {
        int c = oc - 64;
        int h = c >> 4, i = c & 15;
        vv[(((size_t)b * 4 + h) * 256 + j) * 16 + i] = s;
    }
}

// ---------------- K4: fused q-proj + attention + out-proj ----------------
// grid: 2*512 = 1024 blocks, 256 thr; 1 thread = 1 query position
__global__ __launch_bounds__(256) void k_attn(const float* __restrict__ x,
                                              const float* __restrict__ wq_t,
                                              const float* __restrict__ wout_t,
                                              const float* __restrict__ kt,
                                              const float* __restrict__ vv,
                                              float* __restrict__ out) {
    __shared__ float xs[64][256];   // 64KB; x tile, later reused for attention output
    int tid = threadIdx.x;
    int b = blockIdx.x >> 9;
    int n = ((blockIdx.x & 511) << 8) + tid;

    const float* xb = x + ((size_t)b << 23) + n;
#pragma unroll 8
    for (int c = 0; c < 64; ++c) xs[c][tid] = xb[(size_t)c << 17];

    // q projection for all 4 heads (scale 1/sqrt(16)=0.25 folded in afterwards)
    float q0[16], q1[16], q2[16], q3[16];
#pragma unroll
    for (int i = 0; i < 16; ++i) { q0[i] = 0.f; q1[i] = 0.f; q2[i] = 0.f; q3[i] = 0.f; }
    for (int c = 0; c < 64; ++c) {
        float xv = xs[c][tid];
        const float* w = wq_t + c * 64;
#pragma unroll
        for (int i = 0; i < 16; ++i) {
            q0[i] += w[i]      * xv;
            q1[i] += w[16 + i] * xv;
            q2[i] += w[32 + i] * xv;
            q3[i] += w[48 + i] * xv;
        }
    }
#pragma unroll
    for (int i = 0; i < 16; ++i) { q0[i] *= 0.25f; q1[i] *= 0.25f; q2[i] *= 0.25f; q3[i] *= 0.25f; }

    // attention per head; sim ~ N(0,1) so exp without max-subtraction is fp32-safe
    auto do_head = [&](const float (&qh)[16], int h) {
        const float* kb = kt + (((size_t)b * 4 + h) << 12);   // *256*16
        const float* vb = vv + (((size_t)b * 4 + h) << 12);
        float o[16];
#pragma unroll
        for (int i = 0; i < 16; ++i) o[i] = 0.f;
        float l = 0.f;
#pragma unroll 2
        for (int j = 0; j < 256; ++j) {
            const float* kr = kb + j * 16;
            float s0 = 0.f, s1 = 0.f, s2 = 0.f, s3 = 0.f;
#pragma unroll
            for (int i = 0; i < 4; ++i) {
                s0 += qh[i]      * kr[i];
                s1 += qh[4 + i]  * kr[4 + i];
                s2 += qh[8 + i]  * kr[8 + i];
                s3 += qh[12 + i] * kr[12 + i];
            }
            float s = (s0 + s1) + (s2 + s3);
            float p = __expf(s);
            l += p;
            const float* vr = vb + j * 16;
#pragma unroll
            for (int i = 0; i < 16; ++i) o[i] += p * vr[i];
        }
        float rl = 1.0f / l;
#pragma unroll
        for (int i = 0; i < 16; ++i) xs[h * 16 + i][tid] = o[i] * rl;
    };
    do_head(q0, 0);
    do_head(q1, 1);
    do_head(q2, 2);
    do_head(q3, 3);

    // out projection
    float f[64];
#pragma unroll
    for (int o = 0; o < 64; ++o) f[o] = 0.f;
    for (int c = 0; c < 64; ++c) {
        float ov = xs[c][tid];
        const float* w = wout_t + c * 64;
#pragma unroll
        for (int o = 0; o < 64; ++o) f[o] += w[o] * ov;
    }
    float* ob = out + ((size_t)b << 23) + n;
#pragma unroll 8
    for (int o = 0; o < 64; ++o) ob[(size_t)o << 17] = f[o];
}

extern "C" void kernel_launch(void* const* d_in, const int* in_sizes, int n_in,
                              void* d_out, int out_size, void* d_ws, size_t ws_size,
                              hipStream_t stream) {
    const float* x    = (const float*)d_in[0];
    const float* wq   = (const float*)d_in[1];
    const float* wkv  = (const float*)d_in[2];
    const float* wout = (const float*)d_in[3];
    float* out = (float*)d_out;
    float* ws = (float*)d_ws;

    float* wt      = ws;                  // 64*512*128      = 4,194,304 floats (16MB)
    float* partial = ws + 4194304;        // 64*2*256*128    = 4,194,304 floats (16MB)
    float* kt      = ws + 8388608;        // 2*4*256*16      = 32768 floats
    float* vv      = kt + 32768;          // 32768 floats
    float* wq_t    = vv + 32768;          // 4096
    float* wout_t  = wq_t + 4096;         // 4096

    k_prep_w  <<<16,   256, 0, stream>>>(wq, wout, wq_t, wout_t);
    k_prep_wkv<<<4096, 256, 0, stream>>>(wkv, wt);
    k_conv    <<<512,  256, 0, stream>>>(x, wt, partial);
    k_reduce  <<<256,  256, 0, stream>>>(partial, kt, vv);
    k_attn    <<<1024, 256, 0, stream>>>(x, wq_t, wout_t, kt, vv, out);
}

// Round 2
// 226.841 us; speedup vs baseline: 2.7061x; 2.7061x over previous
//
#include <hip/hip_runtime.h>
#include <hip/hip_bf16.h>

#define NPOS 131072   // 32*64*64 positions per batch

typedef __attribute__((ext_vector_type(8))) short short8;
typedef __attribute__((ext_vector_type(4))) float floatx4;
typedef unsigned int uint32;
typedef unsigned short ushort16_t;

__device__ __forceinline__ unsigned short bf16b(float v) {
    __hip_bfloat16 h = __float2bfloat16(v);
    return __builtin_bit_cast(unsigned short, h);
}
__device__ __forceinline__ uint32 cvtpk(float lo, float hi) {
    uint32 r;
    asm("v_cvt_pk_bf16_f32 %0, %1, %2" : "=v"(r) : "v"(lo), "v"(hi));
    return r;
}
#if __has_builtin(__builtin_amdgcn_exp2f)
#define EXP2(x) __builtin_amdgcn_exp2f(x)
#else
#define EXP2(x) exp2f(x)
#endif
#if __has_builtin(__builtin_amdgcn_rcpf)
#define RCPF(x) __builtin_amdgcn_rcpf(x)
#else
#define RCPF(x) (1.0f / (x))
#endif

// ---------------- K1: transpose w_kv[oc][ic][term] -> wt[ic][term][oc] ----------------
__global__ void k_prep_wkv(const float* __restrict__ wkv, float* __restrict__ wt) {
    __shared__ float tile[32][33];
    int bid = blockIdx.x;
    int ic = bid >> 6;
    int tb = (bid >> 2) & 15;
    int ob = bid & 3;
    int lane = threadIdx.x & 31;
    int row  = threadIdx.x >> 5;
#pragma unroll
    for (int rr = 0; rr < 4; ++rr) {
        int r = row + rr * 8;
        tile[r][lane] = wkv[((size_t)(ob * 32 + r) * 64 + ic) * 512 + tb * 32 + lane];
    }
    __syncthreads();
#pragma unroll
    for (int rr = 0; rr < 4; ++rr) {
        int r = row + rr * 8;
        wt[((size_t)ic * 512 + tb * 32 + r) * 128 + ob * 32 + lane] = tile[lane][r];
    }
}

// ---------------- K2: strided conv, split-K over ic, both batches per block ----------------
// grid: ic(64) x dz(4) = 256 blocks, 256 thr
// partial[ic][b][pos(256)][oc(128)]
__global__ __launch_bounds__(256) void k_conv2(const float* __restrict__ x,
                                               const float* __restrict__ wt,
                                               float* __restrict__ partial) {
    __shared__ float pl[2][4096];   // transposed planes: [row(y)][ (x&7)*8 + (x>>3) ]
    int bid = blockIdx.x;
    int ic = bid >> 2, dz = bid & 3;
    int tid = threadIdx.x;
    int og = tid & 31;      // oc group: oc = og*4..og*4+3
    int dy = tid >> 5;      // 0..7

    float4 acc0[8], acc1[8];
#pragma unroll
    for (int d = 0; d < 8; ++d) { acc0[d] = make_float4(0,0,0,0); acc1[d] = make_float4(0,0,0,0); }

    const float* xb0 = x + (size_t)ic * NPOS + (size_t)dz * 32768;
    const float* xb1 = xb0 + (size_t)64 * NPOS;
    const float* wb  = wt + (size_t)ic * 65536 + og * 4;

    for (int rz = 0; rz < 8; ++rz) {
        __syncthreads();
#pragma unroll
        for (int t2 = 0; t2 < 4; ++t2) {
            int e = t2 * 1024 + tid * 4;
            int row = e >> 6, x0 = e & 63;
            float4 v0 = *(const float4*)(xb0 + (size_t)rz * 4096 + e);
            float4 v1 = *(const float4*)(xb1 + (size_t)rz * 4096 + e);
            float* r0 = pl[0] + row * 64;
            float* r1 = pl[1] + row * 64;
            int p0 = ((x0 + 0) & 7) * 8 + ((x0 + 0) >> 3);
            int p1 = ((x0 + 1) & 7) * 8 + ((x0 + 1) >> 3);
            int p2 = ((x0 + 2) & 7) * 8 + ((x0 + 2) >> 3);
            int p3 = ((x0 + 3) & 7) * 8 + ((x0 + 3) >> 3);
            r0[p0] = v0.x; r0[p1] = v0.y; r0[p2] = v0.z; r0[p3] = v0.w;
            r1[p0] = v1.x; r1[p1] = v1.y; r1[p2] = v1.z; r1[p3] = v1.w;
        }
        __syncthreads();
        for (int ry = 0; ry < 8; ++ry) {
            int rowo = (dy * 8 + ry) * 64;
#pragma unroll
            for (int rx = 0; rx < 8; ++rx) {
                float4 w = *(const float4*)(wb + (size_t)(rz * 64 + ry * 8 + rx) * 128);
                const float* q0 = pl[0] + rowo + rx * 8;
                const float* q1 = pl[1] + rowo + rx * 8;
#pragma unroll
                for (int dxk = 0; dxk < 8; ++dxk) {
                    float v0 = q0[dxk], v1 = q1[dxk];
                    acc0[dxk].x += v0 * w.x; acc0[dxk].y += v0 * w.y;
                    acc0[dxk].z += v0 * w.z; acc0[dxk].w += v0 * w.w;
                    acc1[dxk].x += v1 * w.x; acc1[dxk].y += v1 * w.y;
                    acc1[dxk].z += v1 * w.z; acc1[dxk].w += v1 * w.w;
                }
            }
        }
    }
    float* pb0 = partial + (((size_t)ic * 2 + 0) * 256 + dz * 64 + dy * 8) * 128 + og * 4;
    float* pb1 = pb0 + (size_t)256 * 128;
#pragma unroll
    for (int dxk = 0; dxk < 8; ++dxk) {
        *(float4*)(pb0 + (size_t)dxk * 128) = acc0[dxk];
        *(float4*)(pb1 + (size_t)dxk * 128) = acc1[dxk];
    }
}

// ---------------- K3: reduce over ic; K -> bf16 [b][h][256][16], V -> bf16 [b][h][16][256] ----------------
__global__ void k_reduce(const float* __restrict__ partial,
                         unsigned short* __restrict__ kt, unsigned short* __restrict__ vt) {
    int gid = blockIdx.x * 256 + threadIdx.x;
    int oc = gid & 127;
    int bp = gid >> 7;          // b*256 + j
    int b = bp >> 8;
    int j = bp & 255;
    const float* p = partial + (size_t)bp * 128 + oc;
    float s = 0.f;
#pragma unroll 8
    for (int ic = 0; ic < 64; ++ic) s += p[(size_t)ic * 65536];
    int h = (oc & 63) >> 4, i = oc & 15;
    if (oc < 64)
        kt[(((size_t)b * 4 + h) * 256 + j) * 16 + i] = bf16b(s);
    else
        vt[(((size_t)b * 4 + h) * 16 + i) * 256 + j] = bf16b(s);
}

// ---------------- K4: fused MFMA q-proj + attention + out-proj ----------------
// grid: 2 * 2048 blocks, 256 thr (4 waves); block = 64 positions; wave w owns n-tile w (16 pos)
__global__ __launch_bounds__(256) void k_attn_mfma(
    const float* __restrict__ x, const float* __restrict__ wq,
    const float* __restrict__ wout, const unsigned short* __restrict__ kt,
    const unsigned short* __restrict__ vt, float* __restrict__ out)
{
    __shared__ __align__(16) unsigned short s_kv[8320];     // wq | per-head {K [256][16], V [16][264]} | wout
    __shared__ __align__(16) unsigned short s_at[64 * 72];  // xT [n][c] bf16, later att [n][c] bf16
    __shared__ __align__(16) unsigned short s_qb[64 * 136]; // Q [n][h*32 + i] bf16, pad halves zeroed
    __shared__ __align__(16) unsigned short s_pb[64 * 264]; // P [n][j] bf16; later y [o][n] f32 [64][68]
    __shared__ float s_l[256];                              // per-head row sums [h][n]

    const int tid  = threadIdx.x;
    const int b    = blockIdx.x >> 11;
    const int n_base = (blockIdx.x & 2047) << 6;
    const int lane = tid & 63;
    const int wv   = tid >> 6;
    const int lc   = lane & 15;
    const int lg   = lane >> 4;
    const int nloc = wv * 16;

    const float QS = 0.36067376022224085f;   // 0.25 * log2(e): logits in exp2 domain

    // ---- stage wq (scaled) ----
#pragma unroll
    for (int r = 0; r < 16; ++r) {
        int idx = r * 256 + tid;
        int o = idx >> 6, c = idx & 63;
        s_kv[o * 72 + c] = bf16b(wq[idx] * QS);
    }
    // ---- stage x tile -> xT[n][c] bf16 ----
    {
        int n_l = tid & 63;
        int c0  = (tid >> 6) * 16;
        const float* xb = x + ((size_t)b << 23) + n_base + n_l;
        uint32* xrow = (uint32*)&s_at[n_l * 72 + c0];
#pragma unroll
        for (int r = 0; r < 8; ++r) {
            float v0 = xb[(size_t)(c0 + 2 * r) << 17];
            float v1 = xb[(size_t)(c0 + 2 * r + 1) << 17];
            xrow[r] = cvtpk(v0, v1);
        }
    }
    // ---- zero Q buffer (pad columns must be 0) ----
    {
        uint32* q32 = (uint32*)s_qb;
#pragma unroll
        for (int r = 0; r < 17; ++r) q32[r * 256 + tid] = 0;
    }
    __syncthreads();

    // ---- Q projection (MFMA): Q[n][o] = x[n][c] * wq[o][c] ----
#pragma unroll
    for (int ot = 0; ot < 4; ++ot) {
        floatx4 c = {0.f, 0.f, 0.f, 0.f};
#pragma unroll
        for (int ks = 0; ks < 2; ++ks) {
            short8 a  = *(const short8*)&s_at[(nloc + lc) * 72 + ks * 32 + lg * 8];
            short8 bb = *(const short8*)&s_kv[(ot * 16 + lc) * 72 + ks * 32 + lg * 8];
            c = __builtin_amdgcn_mfma_f32_16x16x32_bf16(a, bb, c, 0, 0, 0);
        }
#pragma unroll
        for (int r = 0; r < 4; ++r)
            s_qb[(nloc + lg * 4 + r) * 136 + ot * 32 + lc] = bf16b(c[r]);
    }

    unsigned short* s_kh = s_kv;             // [256][16] bf16
    unsigned short* s_vh = s_kv + 4096;      // [16][264] bf16 (row pad 8)

#pragma unroll 1
    for (int h = 0; h < 4; ++h) {
        __syncthreads();    // prev head compute done (h=0: wq reads done)
        // ---- stage K_h, V_h into LDS ----
        {
            const uint32* ksrc = (const uint32*)(kt + (size_t)b * 16384 + h * 4096);
            uint32* kdst = (uint32*)s_kh;
#pragma unroll
            for (int r = 0; r < 8; ++r) kdst[r * 256 + tid] = ksrc[r * 256 + tid];
            int i  = tid >> 4;
            int jc = (tid & 15) * 16;
            const uint32* vs = (const uint32*)(vt + (size_t)b * 16384 + h * 4096 + i * 256 + jc);
            uint32* vd = (uint32*)s_vh + i * 132 + jc / 2;
#pragma unroll
            for (int r = 0; r < 8; ++r) vd[r] = vs[r];
        }
        __syncthreads();

        // ---- S^T = K * Q^T  (contraction 16 padded to 32; Q pad cols are 0) ----
        float lp = 0.f;
        uint32* prow = (uint32*)&s_pb[(nloc + lc) * 264];
#pragma unroll 4
        for (int jt = 0; jt < 16; ++jt) {
            floatx4 c = {0.f, 0.f, 0.f, 0.f};
            short8 a  = *(const short8*)&s_kh[(jt * 16 + lc) * 16 + (lg & 1) * 8]; // k-slots 16..31: garbage*0
            short8 bb = *(const short8*)&s_qb[(nloc + lc) * 136 + h * 32 + lg * 8];
            c = __builtin_amdgcn_mfma_f32_16x16x32_bf16(a, bb, c, 0, 0, 0);
            float p0 = EXP2(c[0]); float p1 = EXP2(c[1]);
            float p2 = EXP2(c[2]); float p3 = EXP2(c[3]);
            lp += (p0 + p1) + (p2 + p3);
            prow[jt * 8 + lg * 2 + 0] = cvtpk(p0, p1);
            prow[jt * 8 + lg * 2 + 1] = cvtpk(p2, p3);
        }
        lp += __shfl_xor(lp, 16, 64);
        lp += __shfl_xor(lp, 32, 64);
        if (lane < 16) s_l[h * 64 + nloc + lane] = lp;

        // ---- PV: att[n][i] = sum_j P[n][j] V[j][i] ----
        floatx4 acc = {0.f, 0.f, 0.f, 0.f};
#pragma unroll
        for (int ks = 0; ks < 8; ++ks) {
            short8 a  = *(const short8*)&s_pb[(nloc + lc) * 264 + ks * 32 + lg * 8];
            short8 bb = *(const short8*)&s_vh[lc * 264 + ks * 32 + lg * 8];
            acc = __builtin_amdgcn_mfma_f32_16x16x32_bf16(a, bb, acc, 0, 0, 0);
        }
#pragma unroll
        for (int r = 0; r < 4; ++r) {
            float rl = RCPF(s_l[h * 64 + nloc + lg * 4 + r]);
            s_at[(nloc + lg * 4 + r) * 72 + h * 16 + lc] = bf16b(acc[r] * rl);
        }
    }

    // ---- stage wout ----
    __syncthreads();
#pragma unroll
    for (int r = 0; r < 16; ++r) {
        int idx = r * 256 + tid;
        int o = idx >> 6, c = idx & 63;
        s_kv[o * 72 + c] = bf16b(wout[idx]);
    }
    __syncthreads();

    // ---- out projection: y[n][o] = att[n][c] * wout[o][c], staged to yb[o][n] f32 ----
    float* yb = (float*)s_pb;   // [64][68]
#pragma unroll
    for (int ot = 0; ot < 4; ++ot) {
        floatx4 c = {0.f, 0.f, 0.f, 0.f};
#pragma unroll
        for (int ks = 0; ks < 2; ++ks) {
            short8 a  = *(const short8*)&s_at[(nloc + lc) * 72 + ks * 32 + lg * 8];
            short8 bb = *(const short8*)&s_kv[(ot * 16 + lc) * 72 + ks * 32 + lg * 8];
            c = __builtin_amdgcn_mfma_f32_16x16x32_bf16(a, bb, c, 0, 0, 0);
        }
#pragma unroll
        for (int r = 0; r < 4; ++r)
            yb[(ot * 16 + lc) * 68 + nloc + lg * 4 + r] = c[r];
    }
    __syncthreads();

    // ---- coalesced copyout ----
    {
        int o = tid >> 2, nc = (tid & 3) * 16;
        float* dst = out + ((size_t)b << 23) + (size_t)o * 131072 + n_base + nc;
        const float* src = (const float*)s_pb + o * 68 + nc;
#pragma unroll
        for (int i = 0; i < 4; ++i)
            *(float4*)(dst + i * 4) = *(const float4*)(src + i * 4);
    }
}

extern "C" void kernel_launch(void* const* d_in, const int* in_sizes, int n_in,
                              void* d_out, int out_size, void* d_ws, size_t ws_size,
                              hipStream_t stream) {
    const float* x    = (const float*)d_in[0];
    const float* wq   = (const float*)d_in[1];
    const float* wkv  = (const float*)d_in[2];
    const float* wout = (const float*)d_in[3];
    float* out = (float*)d_out;
    float* ws = (float*)d_ws;

    float* wt      = ws;                    // 64*512*128 = 4,194,304 f (16MB)
    float* partial = ws + 4194304;          // 64*2*256*128 = 4,194,304 f (16MB)
    unsigned short* ktu = (unsigned short*)(ws + 8388608);  // [2][4][256][16] bf16
    unsigned short* vtu = ktu + 32768;                      // [2][4][16][256] bf16

    k_prep_wkv <<<4096, 256, 0, stream>>>(wkv, wt);
    k_conv2    <<<256,  256, 0, stream>>>(x, wt, partial);
    k_reduce   <<<256,  256, 0, stream>>>(partial, ktu, vtu);
    k_attn_mfma<<<4096, 256, 0, stream>>>(x, wq, wout, ktu, vtu, out);
}

// Round 4
// 137.316 us; speedup vs baseline: 4.4704x; 1.6520x over previous
//
#include <hip/hip_runtime.h>
#include <hip/hip_bf16.h>

#define NPOS 131072   // 32*64*64 positions per batch

typedef __attribute__((ext_vector_type(8))) short short8;
typedef __attribute__((ext_vector_type(4))) float floatx4;
typedef unsigned int uint32;

__device__ __forceinline__ unsigned short bf16b(float v) {
    __hip_bfloat16 h = __float2bfloat16(v);
    return __builtin_bit_cast(unsigned short, h);
}
__device__ __forceinline__ uint32 cvtpk(float lo, float hi) {
    uint32 r;
    asm("v_cvt_pk_bf16_f32 %0, %1, %2" : "=v"(r) : "v"(lo), "v"(hi));
    return r;
}
#if __has_builtin(__builtin_amdgcn_exp2f)
#define EXP2(x) __builtin_amdgcn_exp2f(x)
#else
#define EXP2(x) exp2f(x)
#endif
#if __has_builtin(__builtin_amdgcn_rcpf)
#define RCPF(x) __builtin_amdgcn_rcpf(x)
#else
#define RCPF(x) (1.0f / (x))
#endif

// ---------------- K1: wkv[oc][ic][term] f32 -> wtb[ic][oc][term] bf16 ----------------
__global__ void k_prep_wkvb(const float* __restrict__ wkv, unsigned short* __restrict__ wtb) {
    int gid = blockIdx.x * 256 + threadIdx.x;   // 0..1048575
    int ic = gid >> 14;
    int oc = (gid >> 7) & 127;
    float4 v = *(const float4*)(wkv + ((size_t)(oc * 64 + ic)) * 512 + (size_t)(gid & 127) * 4);
    uint32* dst = (uint32*)(wtb + (size_t)gid * 4);
    dst[0] = cvtpk(v.x, v.y);
    dst[1] = cvtpk(v.z, v.w);
}

// ---------------- K2: conv as bf16 MFMA GEMM, split-K over ic ----------------
// grid 512: ic = bid&63 (XCD-affine), b = (bid>>6)&1, pz = bid>>7; 256 thr (4 waves)
__global__ __launch_bounds__(256) void k_conv_mfma(const float* __restrict__ x,
                                                   const unsigned short* __restrict__ wtb,
                                                   float* __restrict__ partial) {
    __shared__ __align__(16) unsigned short As[64 * 72];    // [patch][k 0..63 pad 72]
    __shared__ __align__(16) unsigned short Bs[128 * 72];   // [oc][k 0..63 pad 72]
    const int bid = blockIdx.x;
    const int ic = bid & 63;
    const int b  = (bid >> 6) & 1;
    const int pz = bid >> 7;
    const int tid = threadIdx.x;
    const int lane = tid & 63, wv = tid >> 6;
    const int lc = lane & 15, lg = lane >> 4;

    floatx4 acc[4][2];
#pragma unroll
    for (int mt = 0; mt < 4; ++mt)
#pragma unroll
        for (int n = 0; n < 2; ++n) acc[mt][n] = {0.f, 0.f, 0.f, 0.f};

    const float* xp = x + ((size_t)b * 64 + ic) * NPOS + (size_t)pz * 8 * 4096;
    const unsigned short* wp = wtb + (size_t)ic * 128 * 512;

    for (int rz = 0; rz < 8; ++rz) {
        __syncthreads();
        // stage A: one z-plane -> patch-major bf16
        const float* plane = xp + (size_t)rz * 4096;
#pragma unroll
        for (int t2 = 0; t2 < 4; ++t2) {
            int e = (t2 * 256 + tid) * 4;
            int y = e >> 6, x0 = e & 63;
            int p = ((y >> 3) << 3) + (x0 >> 3);
            int k = ((y & 7) << 3) + (x0 & 7);
            float4 v = *(const float4*)(plane + e);
            uint32* dst = (uint32*)&As[p * 72 + k];
            dst[0] = cvtpk(v.x, v.y);
            dst[1] = cvtpk(v.z, v.w);
        }
        // stage B: wtb[ic][oc][rz*64 .. +63]  (32 bf16 per half => 4 x uint4)
        {
            int oc = tid >> 1, hf = tid & 1;
            const uint4* src = (const uint4*)(wp + (size_t)oc * 512 + rz * 64 + hf * 32);
            uint4* dst = (uint4*)&Bs[oc * 72 + hf * 32];
#pragma unroll
            for (int r = 0; r < 4; ++r) dst[r] = src[r];
        }
        __syncthreads();
        // MFMA: wave wv owns N-tiles {2wv, 2wv+1}, all 4 M-tiles
#pragma unroll
        for (int ks = 0; ks < 2; ++ks) {
            short8 bb0 = *(const short8*)&Bs[((wv * 2 + 0) * 16 + lc) * 72 + ks * 32 + lg * 8];
            short8 bb1 = *(const short8*)&Bs[((wv * 2 + 1) * 16 + lc) * 72 + ks * 32 + lg * 8];
#pragma unroll
            for (int mt = 0; mt < 4; ++mt) {
                short8 a = *(const short8*)&As[(mt * 16 + lc) * 72 + ks * 32 + lg * 8];
                acc[mt][0] = __builtin_amdgcn_mfma_f32_16x16x32_bf16(a, bb0, acc[mt][0], 0, 0, 0);
                acc[mt][1] = __builtin_amdgcn_mfma_f32_16x16x32_bf16(a, bb1, acc[mt][1], 0, 0, 0);
            }
        }
    }
    // epilogue: partial[ic][b][pz*64 + m][oc]
    float* pb = partial + (((size_t)ic * 2 + b) * 256 + pz * 64) * 128;
#pragma unroll
    for (int mt = 0; mt < 4; ++mt)
#pragma unroll
        for (int ntl = 0; ntl < 2; ++ntl) {
            int oc = (wv * 2 + ntl) * 16 + lc;
#pragma unroll
            for (int r = 0; r < 4; ++r) {
                int m = mt * 16 + lg * 4 + r;
                pb[(size_t)m * 128 + oc] = acc[mt][ntl][r];
            }
        }
}

// ---------------- K3: reduce over ic; K -> bf16 [b][h][256][16], V -> bf16 [b][h][16][256] ----------------
__global__ void k_reduce(const float* __restrict__ partial,
                         unsigned short* __restrict__ kt, unsigned short* __restrict__ vt) {
    int gid = blockIdx.x * 256 + threadIdx.x;
    int oc = gid & 127;
    int bp = gid >> 7;          // b*256 + j
    int b = bp >> 8;
    int j = bp & 255;
    const float* p = partial + (size_t)bp * 128 + oc;
    float s = 0.f;
#pragma unroll 8
    for (int ic = 0; ic < 64; ++ic) s += p[(size_t)ic * 65536];
    int h = (oc & 63) >> 4, i = oc & 15;
    if (oc < 64)
        kt[(((size_t)b * 4 + h) * 256 + j) * 16 + i] = bf16b(s);
    else
        vt[(((size_t)b * 4 + h) * 16 + i) * 256 + j] = bf16b(s);
}

// ---------------- K4: fused MFMA q-proj + attention + out-proj (unchanged) ----------------
__global__ __launch_bounds__(256) void k_attn_mfma(
    const float* __restrict__ x, const float* __restrict__ wq,
    const float* __restrict__ wout, const unsigned short* __restrict__ kt,
    const unsigned short* __restrict__ vt, float* __restrict__ out)
{
    __shared__ __align__(16) unsigned short s_kv[8320];     // wq | per-head {K [256][16], V [16][264]} | wout
    __shared__ __align__(16) unsigned short s_at[64 * 72];  // xT [n][c] bf16, later att [n][c] bf16
    __shared__ __align__(16) unsigned short s_qb[64 * 136]; // Q [n][h*32 + i] bf16, pad halves zeroed
    __shared__ __align__(16) unsigned short s_pb[64 * 264]; // P [n][j] bf16; later y [o][n] f32 [64][68]
    __shared__ float s_l[256];                              // per-head row sums [h][n]

    const int tid  = threadIdx.x;
    const int b    = blockIdx.x >> 11;
    const int n_base = (blockIdx.x & 2047) << 6;
    const int lane = tid & 63;
    const int wv   = tid >> 6;
    const int lc   = lane & 15;
    const int lg   = lane >> 4;
    const int nloc = wv * 16;

    const float QS = 0.36067376022224085f;   // 0.25 * log2(e): logits in exp2 domain

    // ---- stage wq (scaled) ----
#pragma unroll
    for (int r = 0; r < 16; ++r) {
        int idx = r * 256 + tid;
        int o = idx >> 6, c = idx & 63;
        s_kv[o * 72 + c] = bf16b(wq[idx] * QS);
    }
    // ---- stage x tile -> xT[n][c] bf16 ----
    {
        int n_l = tid & 63;
        int c0  = (tid >> 6) * 16;
        const float* xb = x + ((size_t)b << 23) + n_base + n_l;
        uint32* xrow = (uint32*)&s_at[n_l * 72 + c0];
#pragma unroll
        for (int r = 0; r < 8; ++r) {
            float v0 = xb[(size_t)(c0 + 2 * r) << 17];
            float v1 = xb[(size_t)(c0 + 2 * r + 1) << 17];
            xrow[r] = cvtpk(v0, v1);
        }
    }
    // ---- zero Q buffer (pad columns must be 0) ----
    {
        uint32* q32 = (uint32*)s_qb;
#pragma unroll
        for (int r = 0; r < 17; ++r) q32[r * 256 + tid] = 0;
    }
    __syncthreads();

    // ---- Q projection (MFMA): Q[n][o] = x[n][c] * wq[o][c] ----
#pragma unroll
    for (int ot = 0; ot < 4; ++ot) {
        floatx4 c = {0.f, 0.f, 0.f, 0.f};
#pragma unroll
        for (int ks = 0; ks < 2; ++ks) {
            short8 a  = *(const short8*)&s_at[(nloc + lc) * 72 + ks * 32 + lg * 8];
            short8 bb = *(const short8*)&s_kv[(ot * 16 + lc) * 72 + ks * 32 + lg * 8];
            c = __builtin_amdgcn_mfma_f32_16x16x32_bf16(a, bb, c, 0, 0, 0);
        }
#pragma unroll
        for (int r = 0; r < 4; ++r)
            s_qb[(nloc + lg * 4 + r) * 136 + ot * 32 + lc] = bf16b(c[r]);
    }

    unsigned short* s_kh = s_kv;             // [256][16] bf16
    unsigned short* s_vh = s_kv + 4096;      // [16][264] bf16 (row pad 8)

#pragma unroll 1
    for (int h = 0; h < 4; ++h) {
        __syncthreads();    // prev head compute done (h=0: wq reads done)
        // ---- stage K_h, V_h into LDS ----
        {
            const uint32* ksrc = (const uint32*)(kt + (size_t)b * 16384 + h * 4096);
            uint32* kdst = (uint32*)s_kh;
#pragma unroll
            for (int r = 0; r < 8; ++r) kdst[r * 256 + tid] = ksrc[r * 256 + tid];
            int i  = tid >> 4;
            int jc = (tid & 15) * 16;
            const uint32* vs = (const uint32*)(vt + (size_t)b * 16384 + h * 4096 + i * 256 + jc);
            uint32* vd = (uint32*)s_vh + i * 132 + jc / 2;
#pragma unroll
            for (int r = 0; r < 8; ++r) vd[r] = vs[r];
        }
        __syncthreads();

        // ---- S^T = K * Q^T  (contraction 16 padded to 32; Q pad cols are 0) ----
        float lp = 0.f;
        uint32* prow = (uint32*)&s_pb[(nloc + lc) * 264];
#pragma unroll 4
        for (int jt = 0; jt < 16; ++jt) {
            floatx4 c = {0.f, 0.f, 0.f, 0.f};
            short8 a  = *(const short8*)&s_kh[(jt * 16 + lc) * 16 + (lg & 1) * 8]; // k-slots 16..31: garbage*0
            short8 bb = *(const short8*)&s_qb[(nloc + lc) * 136 + h * 32 + lg * 8];
            c = __builtin_amdgcn_mfma_f32_16x16x32_bf16(a, bb, c, 0, 0, 0);
            float p0 = EXP2(c[0]); float p1 = EXP2(c[1]);
            float p2 = EXP2(c[2]); float p3 = EXP2(c[3]);
            lp += (p0 + p1) + (p2 + p3);
            prow[jt * 8 + lg * 2 + 0] = cvtpk(p0, p1);
            prow[jt * 8 + lg * 2 + 1] = cvtpk(p2, p3);
        }
        lp += __shfl_xor(lp, 16, 64);
        lp += __shfl_xor(lp, 32, 64);
        if (lane < 16) s_l[h * 64 + nloc + lane] = lp;

        // ---- PV: att[n][i] = sum_j P[n][j] V[j][i] ----
        floatx4 acc = {0.f, 0.f, 0.f, 0.f};
#pragma unroll
        for (int ks = 0; ks < 8; ++ks) {
            short8 a  = *(const short8*)&s_pb[(nloc + lc) * 264 + ks * 32 + lg * 8];
            short8 bb = *(const short8*)&s_vh[lc * 264 + ks * 32 + lg * 8];
            acc = __builtin_amdgcn_mfma_f32_16x16x32_bf16(a, bb, acc, 0, 0, 0);
        }
#pragma unroll
        for (int r = 0; r < 4; ++r) {
            float rl = RCPF(s_l[h * 64 + nloc + lg * 4 + r]);
            s_at[(nloc + lg * 4 + r) * 72 + h * 16 + lc] = bf16b(acc[r] * rl);
        }
    }

    // ---- stage wout ----
    __syncthreads();
#pragma unroll
    for (int r = 0; r < 16; ++r) {
        int idx = r * 256 + tid;
        int o = idx >> 6, c = idx & 63;
        s_kv[o * 72 + c] = bf16b(wout[idx]);
    }
    __syncthreads();

    // ---- out projection: y[n][o] = att[n][c] * wout[o][c], staged to yb[o][n] f32 ----
    float* yb = (float*)s_pb;   // [64][68]
#pragma unroll
    for (int ot = 0; ot < 4; ++ot) {
        floatx4 c = {0.f, 0.f, 0.f, 0.f};
#pragma unroll
        for (int ks = 0; ks < 2; ++ks) {
            short8 a  = *(const short8*)&s_at[(nloc + lc) * 72 + ks * 32 + lg * 8];
            short8 bb = *(const short8*)&s_kv[(ot * 16 + lc) * 72 + ks * 32 + lg * 8];
            c = __builtin_amdgcn_mfma_f32_16x16x32_bf16(a, bb, c, 0, 0, 0);
        }
#pragma unroll
        for (int r = 0; r < 4; ++r)
            yb[(ot * 16 + lc) * 68 + nloc + lg * 4 + r] = c[r];
    }
    __syncthreads();

    // ---- coalesced copyout ----
    {
        int o = tid >> 2, nc = (tid & 3) * 16;
        float* dst = out + ((size_t)b << 23) + (size_t)o * 131072 + n_base + nc;
        const float* src = (const float*)s_pb + o * 68 + nc;
#pragma unroll
        for (int i = 0; i < 4; ++i)
            *(float4*)(dst + i * 4) = *(const float4*)(src + i * 4);
    }
}

extern "C" void kernel_launch(void* const* d_in, const int* in_sizes, int n_in,
                              void* d_out, int out_size, void* d_ws, size_t ws_size,
                              hipStream_t stream) {
    const float* x    = (const float*)d_in[0];
    const float* wq   = (const float*)d_in[1];
    const float* wkv  = (const float*)d_in[2];
    const float* wout = (const float*)d_in[3];
    float* out = (float*)d_out;
    float* ws = (float*)d_ws;

    unsigned short* wtb = (unsigned short*)ws;          // [64][128][512] bf16 = 8 MB
    float* partial = ws + 2097152;                      // [64][2][256][128] f32 = 16 MB
    unsigned short* ktu = (unsigned short*)(ws + 2097152 + 4194304);  // [2][4][256][16] bf16
    unsigned short* vtu = ktu + 32768;                                // [2][4][16][256] bf16

    k_prep_wkvb<<<4096, 256, 0, stream>>>(wkv, wtb);
    k_conv_mfma<<<512,  256, 0, stream>>>(x, wtb, partial);
    k_reduce   <<<256,  256, 0, stream>>>(partial, ktu, vtu);
    k_attn_mfma<<<4096, 256, 0, stream>>>(x, wq, wout, ktu, vtu, out);
}